// Round 1
// baseline (1721.017 us; speedup 1.0000x reference)
//
#include <hip/hip_runtime.h>
#include <cstddef>

#define TPB 256

// Block-wide reduction of two accumulators (sum, sumsq) across 256 threads.
__device__ __forceinline__ void bred2(float& a, float& b, float* red) {
    __syncthreads();  // protect scratch reuse + order prior LDS writes
    #pragma unroll
    for (int off = 32; off > 0; off >>= 1) {
        a += __shfl_down(a, off);
        b += __shfl_down(b, off);
    }
    const int lane = threadIdx.x & 63;
    const int wv = threadIdx.x >> 6;
    if (lane == 0) { red[wv * 2] = a; red[wv * 2 + 1] = b; }
    __syncthreads();
    if (threadIdx.x == 0) {
        float sa = 0.f, sb = 0.f;
        #pragma unroll
        for (int i = 0; i < TPB / 64; i++) { sa += red[2 * i]; sb += red[2 * i + 1]; }
        red[0] = sa; red[1] = sb;
    }
    __syncthreads();
    a = red[0]; b = red[1];
}

__device__ __forceinline__ float silu_f(float v) { return v / (1.f + expf(-v)); }

struct GatePtrs { const float* wg[5]; };

// Task-conditioned top-2 softmax gating for all 5 stages.
// grid = (5 stages), block = 64 (one thread per batch element).
__global__ void gate_kernel(const float* __restrict__ gi, GatePtrs gp,
                            const int* __restrict__ taskp,
                            int* __restrict__ gidx, float* __restrict__ gw) {
    const int s = blockIdx.x;
    const int b = threadIdx.x;
    const int task = taskp[0];
    const float* wg = gp.wg[s] + (size_t)task * 16 * 8;
    float l[8];
    #pragma unroll
    for (int e = 0; e < 8; e++) l[e] = 0.f;
    for (int d = 0; d < 16; d++) {
        float v = gi[b * 16 + d];
        #pragma unroll
        for (int e = 0; e < 8; e++) l[e] += v * wg[d * 8 + e];
    }
    float mx = l[0];
    #pragma unroll
    for (int e = 1; e < 8; e++) mx = fmaxf(mx, l[e]);
    float p[8]; float sum = 0.f;
    #pragma unroll
    for (int e = 0; e < 8; e++) { p[e] = expf(l[e] - mx); sum += p[e]; }
    // top-2, lowest index wins ties (lax.top_k semantics)
    int i0 = 0;
    #pragma unroll
    for (int e = 1; e < 8; e++) if (p[e] > p[i0]) i0 = e;
    int i1 = (i0 == 0) ? 1 : 0;
    #pragma unroll
    for (int e = 0; e < 8; e++) if (e != i0 && p[e] > p[i1]) i1 = e;
    const float denom = p[i0] + p[i1];
    const int base = (s * 64 + b) * 2;
    gidx[base] = i0; gidx[base + 1] = i1;
    gw[base] = p[i0] / denom; gw[base + 1] = p[i1] / denom;
}

// Fused pw1 -> GN -> SiLU -> dw -> GN -> SiLU for one (batch, slot, 4-ch group).
// GN groups are 4 channels and depthwise conv preserves channels, so both GNs
// are block-local. CHUNK=4: keep all 4 channels of the pw1 map in LDS.
// CHUNK=1 (stage 1, map too big): two-pass, recompute pw1 per channel.
template <int CIN, int CEXP, int KS, int STRIDE, int H, int W, int HO, int WO, int CHUNK>
__global__ __launch_bounds__(TPB) void dsc_ab(
    const float* __restrict__ xin, const float* __restrict__ w1,
    const float* __restrict__ g1s, const float* __restrict__ g1b,
    const float* __restrict__ w2,
    const float* __restrict__ g2s, const float* __restrict__ g2b,
    const int* __restrict__ gidx, float* __restrict__ act2) {
    constexpr int HW = H * W, HWO = HO * WO, P = KS / 2;
    const int b = blockIdx.x, slot = blockIdx.y, g = blockIdx.z;
    const int tid = threadIdx.x;
    const int e = gidx[b * 2 + slot];

    __shared__ float buf1[CHUNK * HW];
    __shared__ float buf2[4 * HWO];
    __shared__ float w1s[4 * CIN];
    __shared__ float w2s[4 * KS * KS];
    __shared__ float sc1[4], bi1[4], sc2[4], bi2[4];
    __shared__ float red[2 * (TPB / 64)];

    for (int i = tid; i < 4 * CIN; i += TPB) {
        int c = i / CIN, ci = i % CIN;
        w1s[i] = w1[((size_t)e * CEXP + g * 4 + c) * CIN + ci];
    }
    for (int i = tid; i < 4 * KS * KS; i += TPB) {
        int c = i / (KS * KS), k = i % (KS * KS);
        w2s[i] = w2[((size_t)e * CEXP + g * 4 + c) * KS * KS + k];
    }
    if (tid < 4) {
        sc1[tid] = g1s[e * CEXP + g * 4 + tid];
        bi1[tid] = g1b[e * CEXP + g * 4 + tid];
        sc2[tid] = g2s[e * CEXP + g * 4 + tid];
        bi2[tid] = g2b[e * CEXP + g * 4 + tid];
    }
    __syncthreads();

    const float* xb = xin + (size_t)b * CIN * HW;
    float t1 = 0.f, t2 = 0.f;  // GN2 stats

    if constexpr (CHUNK == 4) {
        float s1 = 0.f, s2 = 0.f;
        for (int p = tid; p < HW; p += TPB) {
            float a[4] = {0.f, 0.f, 0.f, 0.f};
            for (int ci = 0; ci < CIN; ci++) {
                float v = xb[ci * HW + p];
                #pragma unroll
                for (int c = 0; c < 4; c++) a[c] += w1s[c * CIN + ci] * v;
            }
            #pragma unroll
            for (int c = 0; c < 4; c++) {
                buf1[c * HW + p] = a[c];
                s1 += a[c]; s2 += a[c] * a[c];
            }
        }
        bred2(s1, s2, red);
        const float mean = s1 / (4.f * HW);
        const float var = s2 / (4.f * HW) - mean * mean;
        const float inv = rsqrtf(var + 1e-5f);
        for (int i = tid; i < 4 * HW; i += TPB) {
            int c = i / HW;
            float v = (buf1[i] - mean) * inv * sc1[c] + bi1[c];
            buf1[i] = silu_f(v);
        }
        __syncthreads();
        for (int i = tid; i < 4 * HWO; i += TPB) {
            int c = i / HWO, p = i % HWO;
            int oh = p / WO, ow = p % WO;
            float acc = 0.f;
            #pragma unroll
            for (int kh = 0; kh < KS; kh++) {
                int ih = oh * STRIDE - P + kh;
                if (ih < 0 || ih >= H) continue;
                #pragma unroll
                for (int kw = 0; kw < KS; kw++) {
                    int iw = ow * STRIDE - P + kw;
                    if (iw < 0 || iw >= W) continue;
                    acc += w2s[c * KS * KS + kh * KS + kw] * buf1[c * HW + ih * W + iw];
                }
            }
            buf2[i] = acc; t1 += acc; t2 += acc * acc;
        }
    } else {
        // Pass 1: GN1 stats only (pw1 is cheap to recompute, CIN small).
        float s1 = 0.f, s2 = 0.f;
        for (int c = 0; c < 4; c++) {
            for (int p = tid; p < HW; p += TPB) {
                float a = 0.f;
                for (int ci = 0; ci < CIN; ci++) a += w1s[c * CIN + ci] * xb[ci * HW + p];
                s1 += a; s2 += a * a;
            }
        }
        bred2(s1, s2, red);
        const float mean = s1 / (4.f * HW);
        const float var = s2 / (4.f * HW) - mean * mean;
        const float inv = rsqrtf(var + 1e-5f);
        // Pass 2: per channel, recompute pw1 -> GN+SiLU -> LDS -> dw conv.
        for (int c = 0; c < 4; c++) {
            for (int p = tid; p < HW; p += TPB) {
                float a = 0.f;
                for (int ci = 0; ci < CIN; ci++) a += w1s[c * CIN + ci] * xb[ci * HW + p];
                float v = (a - mean) * inv * sc1[c] + bi1[c];
                buf1[p] = silu_f(v);
            }
            __syncthreads();
            for (int p = tid; p < HWO; p += TPB) {
                int oh = p / WO, ow = p % WO;
                float acc = 0.f;
                #pragma unroll
                for (int kh = 0; kh < KS; kh++) {
                    int ih = oh * STRIDE - P + kh;
                    if (ih < 0 || ih >= H) continue;
                    #pragma unroll
                    for (int kw = 0; kw < KS; kw++) {
                        int iw = ow * STRIDE - P + kw;
                        if (iw < 0 || iw >= W) continue;
                        acc += w2s[c * KS * KS + kh * KS + kw] * buf1[ih * W + iw];
                    }
                }
                buf2[c * HWO + p] = acc; t1 += acc; t2 += acc * acc;
            }
            __syncthreads();
        }
    }

    bred2(t1, t2, red);
    const float mean2 = t1 / (4.f * HWO);
    const float var2 = t2 / (4.f * HWO) - mean2 * mean2;
    const float inv2 = rsqrtf(var2 + 1e-5f);
    float* ao = act2 + (((size_t)(b * 2 + slot)) * CEXP + g * 4) * HWO;
    for (int i = tid; i < 4 * HWO; i += TPB) {
        int c = i / HWO;
        float v = (buf2[i] - mean2) * inv2 * sc2[c] + bi2[c];
        ao[i] = silu_f(v);
    }
}

// pw3 -> GN -> gate-weighted sum over the 2 slots, for one (batch, 4-ch out group).
template <int CEXP, int COUT, int HWO>
__global__ __launch_bounds__(TPB) void dsc_c(
    const float* __restrict__ act2, const float* __restrict__ w3,
    const float* __restrict__ g3s, const float* __restrict__ g3b,
    const int* __restrict__ gidx, const float* __restrict__ gw,
    float* __restrict__ xout) {
    const int b = blockIdx.x, go = blockIdx.y;
    const int tid = threadIdx.x;
    __shared__ float w3s[4 * CEXP];
    __shared__ float bufc[4 * HWO];
    __shared__ float accs[4 * HWO];
    __shared__ float sc[4], bi[4];
    __shared__ float red[2 * (TPB / 64)];

    for (int i = tid; i < 4 * HWO; i += TPB) accs[i] = 0.f;

    for (int slot = 0; slot < 2; slot++) {
        const int e = gidx[b * 2 + slot];
        const float wgt = gw[b * 2 + slot];
        for (int i = tid; i < 4 * CEXP; i += TPB) {
            int c = i / CEXP, ce = i % CEXP;
            w3s[i] = w3[((size_t)e * COUT + go * 4 + c) * CEXP + ce];
        }
        if (tid < 4) {
            sc[tid] = g3s[e * COUT + go * 4 + tid];
            bi[tid] = g3b[e * COUT + go * 4 + tid];
        }
        __syncthreads();
        const float* ab = act2 + ((size_t)(b * 2 + slot)) * CEXP * HWO;
        float s1 = 0.f, s2 = 0.f;
        for (int p = tid; p < HWO; p += TPB) {
            float a[4] = {0.f, 0.f, 0.f, 0.f};
            for (int ce = 0; ce < CEXP; ce++) {
                float v = ab[ce * HWO + p];
                #pragma unroll
                for (int c = 0; c < 4; c++) a[c] += w3s[c * CEXP + ce] * v;
            }
            #pragma unroll
            for (int c = 0; c < 4; c++) {
                bufc[c * HWO + p] = a[c];
                s1 += a[c]; s2 += a[c] * a[c];
            }
        }
        bred2(s1, s2, red);
        const float mean = s1 / (4.f * HWO);
        const float var = s2 / (4.f * HWO) - mean * mean;
        const float inv = rsqrtf(var + 1e-5f);
        for (int i = tid; i < 4 * HWO; i += TPB) {
            int c = i / HWO;
            accs[i] += wgt * ((bufc[i] - mean) * inv * sc[c] + bi[c]);
        }
        __syncthreads();
    }
    float* xo = xout + ((size_t)b * COUT + go * 4) * HWO;
    for (int i = tid; i < 4 * HWO; i += TPB) xo[i] = accs[i];
}

// patchify (B,32,20,20) -> (B,25,512) + pos embed; also writes the scalar loss=0.
__global__ void patchify_kernel(const float* __restrict__ x, const float* __restrict__ ppe,
                                float* __restrict__ out) {
    const int idx = blockIdx.x * TPB + threadIdx.x;
    if (idx < 64 * 25 * 512) {
        int d = idx & 511;
        int p = (idx >> 9) % 25;
        int b = idx / (25 * 512);
        int c = d & 31;
        int j = (d >> 5) & 3;
        int i = d >> 7;
        int ph = p / 5, pw = p % 5;
        out[idx] = x[((b * 32 + c) * 20 + ph * 4 + i) * 20 + pw * 4 + j] + ppe[p * 512 + d];
    }
    if (idx == 0) out[64 * 25 * 512] = 0.f;
}

extern "C" void kernel_launch(void* const* d_in, const int* in_sizes, int n_in,
                              void* d_out, int out_size, void* d_ws, size_t ws_size,
                              hipStream_t stream) {
    const float* gate_input = (const float*)d_in[0];
    const float* expert_input = (const float*)d_in[1];
    const float* ppe = (const float*)d_in[2];
    const int* taskp = (const int*)d_in[53];
    auto in = [&](int s, int k) { return (const float*)d_in[3 + s * 10 + k]; };
    // k: 0 wg, 1 w1, 2 g1s, 3 g1b, 4 w2, 5 g2s, 6 g2b, 7 w3, 8 g3s, 9 g3b

    char* ws = (char*)d_ws;
    int* gidx = (int*)ws;                                    // 5*64*2 ints
    float* gw = (float*)(ws + 4096);                         // 5*64*2 floats
    float* x0 = (float*)(ws + 8192);                         // up to 13.63 MB
    float* x1 = (float*)(ws + 8192 + 13631488);              // up to 13.63 MB
    float* act2 = (float*)(ws + 8192 + 2 * 13631488);        // up to 52.43 MB

    GatePtrs gp;
    for (int s = 0; s < 5; s++) gp.wg[s] = in(s, 0);
    gate_kernel<<<5, 64, 0, stream>>>(gate_input, gp, taskp, gidx, gw);

    // Stage 1: (B,3,80,80) -> (B,16,40,40)  [k=7, s=2]
    dsc_ab<3, 32, 7, 2, 80, 80, 40, 40, 1><<<dim3(64, 2, 8), TPB, 0, stream>>>(
        expert_input, in(0, 1), in(0, 2), in(0, 3), in(0, 4), in(0, 5), in(0, 6),
        gidx + 0 * 128, act2);
    dsc_c<32, 16, 1600><<<dim3(64, 4), TPB, 0, stream>>>(
        act2, in(0, 7), in(0, 8), in(0, 9), gidx + 0 * 128, gw + 0 * 128, x0);

    // Stage 2: (B,16,40,40) -> (B,32,40,40)  [k=3, s=1]
    dsc_ab<16, 64, 3, 1, 40, 40, 40, 40, 4><<<dim3(64, 2, 16), TPB, 0, stream>>>(
        x0, in(1, 1), in(1, 2), in(1, 3), in(1, 4), in(1, 5), in(1, 6),
        gidx + 1 * 128, act2);
    dsc_c<64, 32, 1600><<<dim3(64, 8), TPB, 0, stream>>>(
        act2, in(1, 7), in(1, 8), in(1, 9), gidx + 1 * 128, gw + 1 * 128, x1);

    // Stage 3: (B,32,40,40) -> (B,64,20,20)  [k=3, s=2]
    dsc_ab<32, 128, 3, 2, 40, 40, 20, 20, 4><<<dim3(64, 2, 32), TPB, 0, stream>>>(
        x1, in(2, 1), in(2, 2), in(2, 3), in(2, 4), in(2, 5), in(2, 6),
        gidx + 2 * 128, act2);
    dsc_c<128, 64, 400><<<dim3(64, 16), TPB, 0, stream>>>(
        act2, in(2, 7), in(2, 8), in(2, 9), gidx + 2 * 128, gw + 2 * 128, x0);

    // Stage 4: (B,64,20,20) -> (B,64,20,20)  [k=3, s=1]
    dsc_ab<64, 256, 3, 1, 20, 20, 20, 20, 4><<<dim3(64, 2, 64), TPB, 0, stream>>>(
        x0, in(3, 1), in(3, 2), in(3, 3), in(3, 4), in(3, 5), in(3, 6),
        gidx + 3 * 128, act2);
    dsc_c<256, 64, 400><<<dim3(64, 16), TPB, 0, stream>>>(
        act2, in(3, 7), in(3, 8), in(3, 9), gidx + 3 * 128, gw + 3 * 128, x1);

    // Stage 5: (B,64,20,20) -> (B,32,20,20)  [k=3, s=1]
    dsc_ab<64, 128, 3, 1, 20, 20, 20, 20, 4><<<dim3(64, 2, 32), TPB, 0, stream>>>(
        x1, in(4, 1), in(4, 2), in(4, 3), in(4, 4), in(4, 5), in(4, 6),
        gidx + 4 * 128, act2);
    dsc_c<128, 32, 400><<<dim3(64, 8), TPB, 0, stream>>>(
        act2, in(4, 7), in(4, 8), in(4, 9), gidx + 4 * 128, gw + 4 * 128, x0);

    patchify_kernel<<<(64 * 25 * 512 + TPB - 1) / TPB, TPB, 0, stream>>>(x0, ppe, (float*)d_out);
}

// Round 2
// 1143.528 us; speedup vs baseline: 1.5050x; 1.5050x over previous
//
#include <hip/hip_runtime.h>
#include <cstddef>

#define TPB 256

__device__ __forceinline__ int rfl(int v) { return __builtin_amdgcn_readfirstlane(v); }
__device__ __forceinline__ float rflf(float v) {
    return __int_as_float(__builtin_amdgcn_readfirstlane(__float_as_int(v)));
}

// Block-wide reduction of two accumulators (sum, sumsq) across 256 threads.
__device__ __forceinline__ void bred2(float& a, float& b, float* red) {
    __syncthreads();
    #pragma unroll
    for (int off = 32; off > 0; off >>= 1) {
        a += __shfl_down(a, off);
        b += __shfl_down(b, off);
    }
    const int lane = threadIdx.x & 63;
    const int wv = threadIdx.x >> 6;
    if (lane == 0) { red[wv * 2] = a; red[wv * 2 + 1] = b; }
    __syncthreads();
    if (threadIdx.x == 0) {
        float sa = 0.f, sb = 0.f;
        #pragma unroll
        for (int i = 0; i < TPB / 64; i++) { sa += red[2 * i]; sb += red[2 * i + 1]; }
        red[0] = sa; red[1] = sb;
    }
    __syncthreads();
    a = red[0]; b = red[1];
}

__device__ __forceinline__ float silu_f(float v) { return v / (1.f + expf(-v)); }

struct GatePtrs { const float* wg[5]; };

// Task-conditioned top-2 softmax gating for all 5 stages. grid=(5), block=64.
__global__ void gate_kernel(const float* __restrict__ gi, GatePtrs gp,
                            const int* __restrict__ taskp,
                            int* __restrict__ gidx, float* __restrict__ gw) {
    const int s = blockIdx.x;
    const int b = threadIdx.x;
    const int task = taskp[0];
    const float* wg = gp.wg[s] + (size_t)task * 16 * 8;
    float l[8];
    #pragma unroll
    for (int e = 0; e < 8; e++) l[e] = 0.f;
    for (int d = 0; d < 16; d++) {
        float v = gi[b * 16 + d];
        #pragma unroll
        for (int e = 0; e < 8; e++) l[e] += v * wg[d * 8 + e];
    }
    float mx = l[0];
    #pragma unroll
    for (int e = 1; e < 8; e++) mx = fmaxf(mx, l[e]);
    float p[8]; float sum = 0.f;
    #pragma unroll
    for (int e = 0; e < 8; e++) { p[e] = expf(l[e] - mx); sum += p[e]; }
    int i0 = 0;
    #pragma unroll
    for (int e = 1; e < 8; e++) if (p[e] > p[i0]) i0 = e;
    int i1 = (i0 == 0) ? 1 : 0;
    #pragma unroll
    for (int e = 0; e < 8; e++) if (e != i0 && p[e] > p[i1]) i1 = e;
    const float denom = p[i0] + p[i1];
    const int base = (s * 64 + b) * 2;
    gidx[base] = i0; gidx[base + 1] = i1;
    gw[base] = p[i0] / denom; gw[base + 1] = p[i1] / denom;
}

// Fused pw1 -> GN -> SiLU -> dw -> GN -> SiLU for one (batch, slot, 4-ch group).
// Weights in registers (SGPR via uniform e), outputs of dw in registers; only
// the post-SiLU pw1 map lives in LDS (padded rows, W+1) for the dw window.
template <int CIN, int CEXP, int KS, int STRIDE, int H, int W, int HO, int WO>
__global__ __launch_bounds__(TPB) void dsc_ab4(
    const float* __restrict__ xin, const float* __restrict__ w1,
    const float* __restrict__ g1s, const float* __restrict__ g1b,
    const float* __restrict__ w2,
    const float* __restrict__ g2s, const float* __restrict__ g2b,
    const int* __restrict__ gidx, float* __restrict__ act2) {
    constexpr int HW = H * W, HWO = HO * WO, P = KS / 2, WP = W + 1;
    constexpr int PXT = (HW + TPB - 1) / TPB;
    constexpr int IT2 = (4 * HWO + TPB - 1) / TPB;
    constexpr int CHK = (CIN < 16) ? CIN : 16;
    const int b = blockIdx.x, slot = blockIdx.y, g = blockIdx.z;
    const int tid = threadIdx.x;
    const int e = rfl(gidx[b * 2 + slot]);

    __shared__ float buf1[4 * H * WP];
    __shared__ float w2s[4 * KS * KS];
    __shared__ float sc2s[4], bi2s[4];
    __shared__ float red[2 * (TPB / 64)];

    if (tid < 4 * KS * KS) {
        int c = tid / (KS * KS), k = tid % (KS * KS);
        w2s[tid] = w2[((size_t)e * CEXP + g * 4 + c) * (KS * KS) + k];
    }
    if (tid < 4) {
        sc2s[tid] = g2s[e * CEXP + g * 4 + tid];
        bi2s[tid] = g2b[e * CEXP + g * 4 + tid];
    }

    const float* xb = xin + (size_t)b * CIN * HW;
    const float* w1e = w1 + ((size_t)e * CEXP + g * 4) * CIN;

    // pw1: acc[c][j] for pixel tid + j*TPB; weights chunked into registers.
    float acc[4][PXT];
    #pragma unroll
    for (int c = 0; c < 4; c++)
        #pragma unroll
        for (int j = 0; j < PXT; j++) acc[c][j] = 0.f;

    for (int cb = 0; cb < CIN; cb += CHK) {
        float wr[4][CHK];
        #pragma unroll
        for (int c = 0; c < 4; c++)
            #pragma unroll
            for (int k = 0; k < CHK; k++) wr[c][k] = w1e[c * CIN + cb + k];
        #pragma unroll
        for (int j = 0; j < PXT; j++) {
            int p = tid + j * TPB;
            if (PXT * TPB == HW || p < HW) {
                #pragma unroll
                for (int k = 0; k < CHK; k++) {
                    float v = xb[(size_t)(cb + k) * HW + p];
                    #pragma unroll
                    for (int c = 0; c < 4; c++) acc[c][j] = fmaf(wr[c][k], v, acc[c][j]);
                }
            }
        }
    }
    float s1 = 0.f, s2 = 0.f;
    #pragma unroll
    for (int c = 0; c < 4; c++)
        #pragma unroll
        for (int j = 0; j < PXT; j++) { s1 += acc[c][j]; s2 += acc[c][j] * acc[c][j]; }
    bred2(s1, s2, red);
    const float mean = s1 / (4.f * HW);
    const float var = s2 / (4.f * HW) - mean * mean;
    const float inv = rsqrtf(var + 1e-5f);
    float sc1r[4], bi1r[4];
    #pragma unroll
    for (int c = 0; c < 4; c++) {
        sc1r[c] = g1s[e * CEXP + g * 4 + c];
        bi1r[c] = g1b[e * CEXP + g * 4 + c];
    }
    #pragma unroll
    for (int j = 0; j < PXT; j++) {
        int p = tid + j * TPB;
        if (PXT * TPB == HW || p < HW) {
            int ph = p / W, pw = p - ph * W;
            #pragma unroll
            for (int c = 0; c < 4; c++)
                buf1[(c * H + ph) * WP + pw] =
                    silu_f((acc[c][j] - mean) * inv * sc1r[c] + bi1r[c]);
        }
    }
    __syncthreads();

    // dw conv from LDS, accumulators in registers.
    float dacc[IT2];
    float t1 = 0.f, t2 = 0.f;
    #pragma unroll
    for (int kk = 0; kk < IT2; kk++) {
        dacc[kk] = 0.f;
        int i = tid + kk * TPB;
        if (IT2 * TPB == 4 * HWO || i < 4 * HWO) {
            int c = i / HWO, p = i - c * HWO;
            int oh = p / WO, ow = p - oh * WO;
            float a = 0.f;
            #pragma unroll
            for (int kh = 0; kh < KS; kh++) {
                int ih = oh * STRIDE - P + kh;
                if (ih < 0 || ih >= H) continue;
                #pragma unroll
                for (int kw = 0; kw < KS; kw++) {
                    int iw = ow * STRIDE - P + kw;
                    if (iw < 0 || iw >= W) continue;
                    a = fmaf(w2s[c * KS * KS + kh * KS + kw], buf1[(c * H + ih) * WP + iw], a);
                }
            }
            dacc[kk] = a; t1 += a; t2 += a * a;
        }
    }
    bred2(t1, t2, red);
    const float mean2 = t1 / (4.f * HWO);
    const float var2 = t2 / (4.f * HWO) - mean2 * mean2;
    const float inv2 = rsqrtf(var2 + 1e-5f);
    float* ao = act2 + ((size_t)(b * 2 + slot) * CEXP + g * 4) * HWO;
    #pragma unroll
    for (int kk = 0; kk < IT2; kk++) {
        int i = tid + kk * TPB;
        if (IT2 * TPB == 4 * HWO || i < 4 * HWO) {
            int c = i / HWO;
            ao[i] = silu_f((dacc[kk] - mean2) * inv2 * sc2s[c] + bi2s[c]);
        }
    }
}

// Stage 1: CIN=3, CEXP=32, 7x7 dw stride 2, 80x80 -> 40x40. Two-pass recompute
// (pw1 is 3 MACs). Weights in registers; buf1 rows padded to 81 to break the
// stride-2 bank conflicts; raw dw output round-trips through act2 (global).
__global__ __launch_bounds__(TPB) void dsc_ab_s1(
    const float* __restrict__ xin, const float* __restrict__ w1,
    const float* __restrict__ g1s, const float* __restrict__ g1b,
    const float* __restrict__ w2,
    const float* __restrict__ g2s, const float* __restrict__ g2b,
    const int* __restrict__ gidx, float* __restrict__ act2) {
    constexpr int H = 80, W = 80, HW = 6400, HO = 40, WO = 40, HWO = 1600;
    constexpr int KS = 7, P = 3, WP = 81, CEXP = 32;
    constexpr int PXT = HW / TPB;            // 25
    constexpr int OXT = (HWO + TPB - 1) / TPB;  // 7
    const int b = blockIdx.x, slot = blockIdx.y, g = blockIdx.z;
    const int tid = threadIdx.x;
    const int e = rfl(gidx[b * 2 + slot]);

    __shared__ float buf1[H * WP];
    __shared__ float red[2 * (TPB / 64)];

    const float* xb = xin + (size_t)b * 3 * HW;
    const float* w1e = w1 + ((size_t)e * CEXP + g * 4) * 3;
    float wr[4][3];
    #pragma unroll
    for (int c = 0; c < 4; c++)
        #pragma unroll
        for (int k = 0; k < 3; k++) wr[c][k] = w1e[c * 3 + k];

    // Pass 1: GN1 stats.
    float s1 = 0.f, s2 = 0.f;
    for (int j = 0; j < PXT; j++) {
        int p = tid + j * TPB;
        float v0 = xb[p], v1 = xb[HW + p], v2 = xb[2 * HW + p];
        #pragma unroll
        for (int c = 0; c < 4; c++) {
            float a = fmaf(wr[c][0], v0, fmaf(wr[c][1], v1, wr[c][2] * v2));
            s1 += a; s2 += a * a;
        }
    }
    bred2(s1, s2, red);
    const float mean = s1 / (4.f * HW);
    const float var = s2 / (4.f * HW) - mean * mean;
    const float inv = rsqrtf(var + 1e-5f);

    float* ao = act2 + ((size_t)(b * 2 + slot) * CEXP + g * 4) * HWO;
    float t1 = 0.f, t2 = 0.f;
    for (int c = 0; c < 4; c++) {  // c is uniform; weight loads scalar per iter
        const float sc1 = g1s[e * CEXP + g * 4 + c];
        const float bi1 = g1b[e * CEXP + g * 4 + c];
        for (int j = 0; j < PXT; j++) {
            int p = tid + j * TPB;
            float a = fmaf(wr[c][0], xb[p], fmaf(wr[c][1], xb[HW + p], wr[c][2] * xb[2 * HW + p]));
            int ph = p / W, pw = p - ph * W;
            buf1[ph * WP + pw] = silu_f((a - mean) * inv * sc1 + bi1);
        }
        __syncthreads();
        const float* w2c = w2 + ((size_t)e * CEXP + g * 4 + c) * 49;
        float wc[49];
        #pragma unroll
        for (int k = 0; k < 49; k++) wc[k] = w2c[k];
        #pragma unroll
        for (int j = 0; j < OXT; j++) {
            int o = tid + j * TPB;
            if (o < HWO) {
                int oh = o / WO, ow = o - oh * WO;
                float a = 0.f;
                #pragma unroll
                for (int kh = 0; kh < KS; kh++) {
                    int ih = oh * 2 - P + kh;
                    if (ih < 0 || ih >= H) continue;
                    #pragma unroll
                    for (int kw = 0; kw < KS; kw++) {
                        int iw = ow * 2 - P + kw;
                        if (iw < 0 || iw >= W) continue;
                        a = fmaf(wc[kh * KS + kw], buf1[ih * WP + iw], a);
                    }
                }
                ao[c * HWO + o] = a;  // raw; normalized below after stats
                t1 += a; t2 += a * a;
            }
        }
        __syncthreads();
    }
    bred2(t1, t2, red);
    const float mean2 = t1 / (4.f * HWO);
    const float var2 = t2 / (4.f * HWO) - mean2 * mean2;
    const float inv2 = rsqrtf(var2 + 1e-5f);
    for (int c = 0; c < 4; c++) {
        const float sc2 = g2s[e * CEXP + g * 4 + c];
        const float bi2 = g2b[e * CEXP + g * 4 + c];
        #pragma unroll
        for (int j = 0; j < OXT; j++) {
            int o = tid + j * TPB;
            if (o < HWO) {
                float a = ao[c * HWO + o];
                ao[c * HWO + o] = silu_f((a - mean2) * inv2 * sc2 + bi2);
            }
        }
    }
}

// pw3 -> GN -> gate-weighted sum over 2 slots, one (batch, 4-out-ch group).
// Weights chunked into registers; accumulators + output in registers; no big LDS.
template <int CEXP, int COUT, int HWO>
__global__ __launch_bounds__(TPB) void dsc_c(
    const float* __restrict__ act2, const float* __restrict__ w3,
    const float* __restrict__ g3s, const float* __restrict__ g3b,
    const int* __restrict__ gidx, const float* __restrict__ gw,
    float* __restrict__ xout) {
    constexpr int PXT = (HWO + TPB - 1) / TPB;
    const int b = blockIdx.x, go = blockIdx.y;
    const int tid = threadIdx.x;
    __shared__ float red[2 * (TPB / 64)];

    float out[4][PXT];
    #pragma unroll
    for (int c = 0; c < 4; c++)
        #pragma unroll
        for (int j = 0; j < PXT; j++) out[c][j] = 0.f;

    for (int slot = 0; slot < 2; slot++) {
        const int e = rfl(gidx[b * 2 + slot]);
        const float wgt = rflf(gw[b * 2 + slot]);
        const float* w3e = w3 + ((size_t)e * COUT + go * 4) * CEXP;
        const float* ab = act2 + (size_t)(b * 2 + slot) * CEXP * HWO;

        float acc[4][PXT];
        #pragma unroll
        for (int c = 0; c < 4; c++)
            #pragma unroll
            for (int j = 0; j < PXT; j++) acc[c][j] = 0.f;

        for (int cb = 0; cb < CEXP; cb += 16) {
            float wr[4][16];
            #pragma unroll
            for (int c = 0; c < 4; c++)
                #pragma unroll
                for (int k = 0; k < 16; k++) wr[c][k] = w3e[c * CEXP + cb + k];
            #pragma unroll
            for (int j = 0; j < PXT; j++) {
                int p = tid + j * TPB;
                if (PXT * TPB == HWO || p < HWO) {
                    #pragma unroll
                    for (int k = 0; k < 16; k++) {
                        float v = ab[(size_t)(cb + k) * HWO + p];
                        #pragma unroll
                        for (int c = 0; c < 4; c++) acc[c][j] = fmaf(wr[c][k], v, acc[c][j]);
                    }
                }
            }
        }
        float s1 = 0.f, s2 = 0.f;
        #pragma unroll
        for (int c = 0; c < 4; c++)
            #pragma unroll
            for (int j = 0; j < PXT; j++) { s1 += acc[c][j]; s2 += acc[c][j] * acc[c][j]; }
        bred2(s1, s2, red);
        const float mean = s1 / (4.f * HWO);
        const float var = s2 / (4.f * HWO) - mean * mean;
        const float inv = rsqrtf(var + 1e-5f);
        float scr[4], bir[4];
        #pragma unroll
        for (int c = 0; c < 4; c++) {
            scr[c] = g3s[e * COUT + go * 4 + c];
            bir[c] = g3b[e * COUT + go * 4 + c];
        }
        #pragma unroll
        for (int c = 0; c < 4; c++)
            #pragma unroll
            for (int j = 0; j < PXT; j++)
                out[c][j] += wgt * ((acc[c][j] - mean) * inv * scr[c] + bir[c]);
    }
    float* xo = xout + ((size_t)b * COUT + go * 4) * HWO;
    #pragma unroll
    for (int c = 0; c < 4; c++)
        #pragma unroll
        for (int j = 0; j < PXT; j++) {
            int p = tid + j * TPB;
            if (PXT * TPB == HWO || p < HWO) xo[c * HWO + p] = out[c][j];
        }
}

// patchify (B,32,20,20) -> (B,25,512) + pos embed; writes scalar loss=0.
__global__ void patchify_kernel(const float* __restrict__ x, const float* __restrict__ ppe,
                                float* __restrict__ out) {
    const int idx = blockIdx.x * TPB + threadIdx.x;
    if (idx < 64 * 25 * 512) {
        int d = idx & 511;
        int p = (idx >> 9) % 25;
        int b = idx / (25 * 512);
        int c = d & 31;
        int j = (d >> 5) & 3;
        int i = d >> 7;
        int ph = p / 5, pw = p % 5;
        out[idx] = x[((b * 32 + c) * 20 + ph * 4 + i) * 20 + pw * 4 + j] + ppe[p * 512 + d];
    }
    if (idx == 0) out[64 * 25 * 512] = 0.f;
}

extern "C" void kernel_launch(void* const* d_in, const int* in_sizes, int n_in,
                              void* d_out, int out_size, void* d_ws, size_t ws_size,
                              hipStream_t stream) {
    const float* gate_input = (const float*)d_in[0];
    const float* expert_input = (const float*)d_in[1];
    const float* ppe = (const float*)d_in[2];
    const int* taskp = (const int*)d_in[53];
    auto in = [&](int s, int k) { return (const float*)d_in[3 + s * 10 + k]; };
    // k: 0 wg, 1 w1, 2 g1s, 3 g1b, 4 w2, 5 g2s, 6 g2b, 7 w3, 8 g3s, 9 g3b

    char* ws = (char*)d_ws;
    int* gidx = (int*)ws;
    float* gw = (float*)(ws + 4096);
    float* x0 = (float*)(ws + 8192);
    float* x1 = (float*)(ws + 8192 + 13631488);
    float* act2 = (float*)(ws + 8192 + 2 * 13631488);

    GatePtrs gp;
    for (int s = 0; s < 5; s++) gp.wg[s] = in(s, 0);
    gate_kernel<<<5, 64, 0, stream>>>(gate_input, gp, taskp, gidx, gw);

    // Stage 1: (B,3,80,80) -> (B,16,40,40)  [k=7, s=2]
    dsc_ab_s1<<<dim3(64, 2, 8), TPB, 0, stream>>>(
        expert_input, in(0, 1), in(0, 2), in(0, 3), in(0, 4), in(0, 5), in(0, 6),
        gidx + 0 * 128, act2);
    dsc_c<32, 16, 1600><<<dim3(64, 4), TPB, 0, stream>>>(
        act2, in(0, 7), in(0, 8), in(0, 9), gidx + 0 * 128, gw + 0 * 128, x0);

    // Stage 2: (B,16,40,40) -> (B,32,40,40)  [k=3, s=1]
    dsc_ab4<16, 64, 3, 1, 40, 40, 40, 40><<<dim3(64, 2, 16), TPB, 0, stream>>>(
        x0, in(1, 1), in(1, 2), in(1, 3), in(1, 4), in(1, 5), in(1, 6),
        gidx + 1 * 128, act2);
    dsc_c<64, 32, 1600><<<dim3(64, 8), TPB, 0, stream>>>(
        act2, in(1, 7), in(1, 8), in(1, 9), gidx + 1 * 128, gw + 1 * 128, x1);

    // Stage 3: (B,32,40,40) -> (B,64,20,20)  [k=3, s=2]
    dsc_ab4<32, 128, 3, 2, 40, 40, 20, 20><<<dim3(64, 2, 32), TPB, 0, stream>>>(
        x1, in(2, 1), in(2, 2), in(2, 3), in(2, 4), in(2, 5), in(2, 6),
        gidx + 2 * 128, act2);
    dsc_c<128, 64, 400><<<dim3(64, 16), TPB, 0, stream>>>(
        act2, in(2, 7), in(2, 8), in(2, 9), gidx + 2 * 128, gw + 2 * 128, x0);

    // Stage 4: (B,64,20,20) -> (B,64,20,20)  [k=3, s=1]
    dsc_ab4<64, 256, 3, 1, 20, 20, 20, 20><<<dim3(64, 2, 64), TPB, 0, stream>>>(
        x0, in(3, 1), in(3, 2), in(3, 3), in(3, 4), in(3, 5), in(3, 6),
        gidx + 3 * 128, act2);
    dsc_c<256, 64, 400><<<dim3(64, 16), TPB, 0, stream>>>(
        act2, in(3, 7), in(3, 8), in(3, 9), gidx + 3 * 128, gw + 3 * 128, x1);

    // Stage 5: (B,64,20,20) -> (B,32,20,20)  [k=3, s=1]
    dsc_ab4<64, 128, 3, 1, 20, 20, 20, 20><<<dim3(64, 2, 32), TPB, 0, stream>>>(
        x1, in(4, 1), in(4, 2), in(4, 3), in(4, 4), in(4, 5), in(4, 6),
        gidx + 4 * 128, act2);
    dsc_c<128, 32, 400><<<dim3(64, 8), TPB, 0, stream>>>(
        act2, in(4, 7), in(4, 8), in(4, 9), gidx + 4 * 128, gw + 4 * 128, x0);

    patchify_kernel<<<(64 * 25 * 512 + TPB - 1) / TPB, TPB, 0, stream>>>(x0, ppe, (float*)d_out);
}

// Round 3
// 655.197 us; speedup vs baseline: 2.6267x; 1.7453x over previous
//
#include <hip/hip_runtime.h>
#include <cstddef>

#define TPB 256

__device__ __forceinline__ int rfl(int v) { return __builtin_amdgcn_readfirstlane(v); }
__device__ __forceinline__ float rflf(float v) {
    return __int_as_float(__builtin_amdgcn_readfirstlane(__float_as_int(v)));
}

// Block-wide reduction of two accumulators (sum, sumsq) across 256 threads.
__device__ __forceinline__ void bred2(float& a, float& b, float* red) {
    __syncthreads();
    #pragma unroll
    for (int off = 32; off > 0; off >>= 1) {
        a += __shfl_down(a, off);
        b += __shfl_down(b, off);
    }
    const int lane = threadIdx.x & 63;
    const int wv = threadIdx.x >> 6;
    if (lane == 0) { red[wv * 2] = a; red[wv * 2 + 1] = b; }
    __syncthreads();
    if (threadIdx.x == 0) {
        float sa = 0.f, sb = 0.f;
        #pragma unroll
        for (int i = 0; i < TPB / 64; i++) { sa += red[2 * i]; sb += red[2 * i + 1]; }
        red[0] = sa; red[1] = sb;
    }
    __syncthreads();
    a = red[0]; b = red[1];
}

__device__ __forceinline__ float silu_f(float v) { return v / (1.f + expf(-v)); }

struct GatePtrs { const float* wg[5]; };

// Task-conditioned top-2 softmax gating for all 5 stages. grid=(5), block=64.
__global__ void gate_kernel(const float* __restrict__ gi, GatePtrs gp,
                            const int* __restrict__ taskp,
                            int* __restrict__ gidx, float* __restrict__ gw) {
    const int s = blockIdx.x;
    const int b = threadIdx.x;
    const int task = taskp[0];
    const float* wg = gp.wg[s] + (size_t)task * 16 * 8;
    float l[8];
    #pragma unroll
    for (int e = 0; e < 8; e++) l[e] = 0.f;
    for (int d = 0; d < 16; d++) {
        float v = gi[b * 16 + d];
        #pragma unroll
        for (int e = 0; e < 8; e++) l[e] += v * wg[d * 8 + e];
    }
    float mx = l[0];
    #pragma unroll
    for (int e = 1; e < 8; e++) mx = fmaxf(mx, l[e]);
    float p[8]; float sum = 0.f;
    #pragma unroll
    for (int e = 0; e < 8; e++) { p[e] = expf(l[e] - mx); sum += p[e]; }
    int i0 = 0;
    #pragma unroll
    for (int e = 1; e < 8; e++) if (p[e] > p[i0]) i0 = e;
    int i1 = (i0 == 0) ? 1 : 0;
    #pragma unroll
    for (int e = 0; e < 8; e++) if (e != i0 && p[e] > p[i1]) i1 = e;
    const float denom = p[i0] + p[i1];
    const int base = (s * 64 + b) * 2;
    gidx[base] = i0; gidx[base + 1] = i1;
    gw[base] = p[i0] / denom; gw[base + 1] = p[i1] / denom;
}

// Fused pw1 -> GN -> SiLU -> dw -> GN -> SiLU for one (batch, slot, 4-ch group).
// Halo-padded LDS map (zero-filled once) -> branch-free dw taps. For STRIDE==2
// the columns are stored even/odd split so dw taps are lane-stride-1.
template <int CIN, int CEXP, int KS, int STRIDE, int H, int W, int HO, int WO>
__global__ __launch_bounds__(TPB) void dsc_ab4(
    const float* __restrict__ xin, const float* __restrict__ w1,
    const float* __restrict__ g1s, const float* __restrict__ g1b,
    const float* __restrict__ w2,
    const float* __restrict__ g2s, const float* __restrict__ g2b,
    const int* __restrict__ gidx, float* __restrict__ act2) {
    constexpr int HW = H * W, HWO = HO * WO;
    constexpr int HP = H + 2, WPL = W + 2, EVW = (W + 2) / 2;
    constexpr int PXT = (HW + TPB - 1) / TPB;
    constexpr int OX = (HWO + TPB - 1) / TPB;
    constexpr int CHK = (CIN < 16) ? CIN : 16;
    const int b = blockIdx.x, slot = blockIdx.y, g = blockIdx.z;
    const int tid = threadIdx.x;
    const int e = rfl(gidx[b * 2 + slot]);

    __shared__ float buf1[4 * HP * WPL];
    __shared__ float red[2 * (TPB / 64)];

    for (int i = tid; i < 4 * HP * WPL; i += TPB) buf1[i] = 0.f;

    const float* xb = xin + (size_t)b * CIN * HW;
    const float* w1e = w1 + ((size_t)e * CEXP + g * 4) * CIN;

    // pw1: acc[c][j] for pixel tid + j*TPB; weights chunked (uniform -> scalar).
    float acc[4][PXT];
    #pragma unroll
    for (int c = 0; c < 4; c++)
        #pragma unroll
        for (int j = 0; j < PXT; j++) acc[c][j] = 0.f;

    for (int cb = 0; cb < CIN; cb += CHK) {
        float wr[4][CHK];
        #pragma unroll
        for (int c = 0; c < 4; c++)
            #pragma unroll
            for (int k = 0; k < CHK; k++) wr[c][k] = w1e[c * CIN + cb + k];
        #pragma unroll
        for (int j = 0; j < PXT; j++) {
            int p = tid + j * TPB;
            if (PXT * TPB == HW || p < HW) {
                #pragma unroll
                for (int k = 0; k < CHK; k++) {
                    float v = xb[(size_t)(cb + k) * HW + p];
                    #pragma unroll
                    for (int c = 0; c < 4; c++) acc[c][j] = fmaf(wr[c][k], v, acc[c][j]);
                }
            }
        }
    }
    float s1 = 0.f, s2 = 0.f;
    #pragma unroll
    for (int c = 0; c < 4; c++)
        #pragma unroll
        for (int j = 0; j < PXT; j++) { s1 += acc[c][j]; s2 += acc[c][j] * acc[c][j]; }
    bred2(s1, s2, red);  // barrier also orders the zero-init before interior writes
    const float mean = s1 / (4.f * HW);
    const float var = s2 / (4.f * HW) - mean * mean;
    const float inv = rsqrtf(var + 1e-5f);
    float sc1r[4], bi1r[4];
    #pragma unroll
    for (int c = 0; c < 4; c++) {
        sc1r[c] = g1s[e * CEXP + g * 4 + c];
        bi1r[c] = g1b[e * CEXP + g * 4 + c];
    }
    #pragma unroll
    for (int j = 0; j < PXT; j++) {
        int p = tid + j * TPB;
        if (PXT * TPB == HW || p < HW) {
            int ph = p / W, pw = p - ph * W;
            int j2 = pw + 1;
            int slotc = (STRIDE == 1) ? j2 : ((j2 & 1) ? EVW + (j2 >> 1) : (j2 >> 1));
            #pragma unroll
            for (int c = 0; c < 4; c++)
                buf1[(c * HP + ph + 1) * WPL + slotc] =
                    silu_f((acc[c][j] - mean) * inv * sc1r[c] + bi1r[c]);
        }
    }
    __syncthreads();

    // dw conv: c-outer (uniform) so weights come from scalar loads.
    float dacc[4][OX];
    float t1 = 0.f, t2 = 0.f;
    for (int c = 0; c < 4; c++) {
        const float* w2c = w2 + ((size_t)e * CEXP + g * 4 + c) * (KS * KS);
        float w2r[KS * KS];
        #pragma unroll
        for (int k = 0; k < KS * KS; k++) w2r[k] = w2c[k];
        #pragma unroll
        for (int kk = 0; kk < OX; kk++) {
            dacc[c][kk] = 0.f;
            int o = tid + kk * TPB;
            if (OX * TPB == HWO || o < HWO) {
                int oh = o / WO, ow = o - oh * WO;
                float a = 0.f;
                #pragma unroll
                for (int kh = 0; kh < KS; kh++) {
                    int row = oh * STRIDE + kh;
                    #pragma unroll
                    for (int kw = 0; kw < KS; kw++) {
                        int off = (STRIDE == 1) ? kw : ((kw & 1) ? EVW + (kw >> 1) : (kw >> 1));
                        a = fmaf(w2r[kh * KS + kw], buf1[(c * HP + row) * WPL + ow + off], a);
                    }
                }
                dacc[c][kk] = a; t1 += a; t2 += a * a;
            }
        }
    }
    bred2(t1, t2, red);
    const float mean2 = t1 / (4.f * HWO);
    const float var2 = t2 / (4.f * HWO) - mean2 * mean2;
    const float inv2 = rsqrtf(var2 + 1e-5f);
    float* ao = act2 + ((size_t)(b * 2 + slot) * CEXP + g * 4) * HWO;
    for (int c = 0; c < 4; c++) {
        const float sc2 = g2s[e * CEXP + g * 4 + c];
        const float bi2 = g2b[e * CEXP + g * 4 + c];
        #pragma unroll
        for (int kk = 0; kk < OX; kk++) {
            int o = tid + kk * TPB;
            if (OX * TPB == HWO || o < HWO)
                ao[c * HWO + o] = silu_f((dacc[c][kk] - mean2) * inv2 * sc2 + bi2);
        }
    }
}

// Stage 1: CIN=3, CEXP=32, 7x7 dw stride 2, 80x80 -> 40x40. Two-pass recompute.
// buf1: halo-padded 85 rows x 88 (even cols at [0,43], odd at [44,87]) so every
// dw tap is branch-free and lane-stride-1 (conflict-free). dw outputs live in
// registers; GN2 normalize writes act2 once. launch_bounds(256,4): VGPR<=128.
__global__ __launch_bounds__(TPB, 4) void dsc_ab_s1(
    const float* __restrict__ xin, const float* __restrict__ w1,
    const float* __restrict__ g1s, const float* __restrict__ g1b,
    const float* __restrict__ w2,
    const float* __restrict__ g2s, const float* __restrict__ g2b,
    const int* __restrict__ gidx, float* __restrict__ act2) {
    constexpr int H = 80, W = 80, HW = 6400, WO = 40, HWO = 1600;
    constexpr int KS = 7, CEXP = 32;
    constexpr int ROWS = 85, RW = 88, EV = 44;
    const int b = blockIdx.x, slot = blockIdx.y, g = blockIdx.z;
    const int tid = threadIdx.x;
    const int e = rfl(gidx[b * 2 + slot]);

    __shared__ float buf1[ROWS * RW];
    __shared__ float red[2 * (TPB / 64)];

    for (int i = tid; i < ROWS * RW; i += TPB) buf1[i] = 0.f;

    const float* xb = xin + (size_t)b * 3 * HW;
    const float* w1e = w1 + ((size_t)e * CEXP + g * 4) * 3;
    float wr[4][3];
    #pragma unroll
    for (int c = 0; c < 4; c++)
        #pragma unroll
        for (int k = 0; k < 3; k++) wr[c][k] = w1e[c * 3 + k];

    // Pass 1: GN1 stats via float4 loads.
    float s1 = 0.f, s2 = 0.f;
    #pragma unroll
    for (int j = 0; j < 7; j++) {
        if (j < 6 || tid < 64) {
            int p4 = (j * TPB + tid) * 4;
            float4 v0 = *(const float4*)(xb + p4);
            float4 v1 = *(const float4*)(xb + HW + p4);
            float4 v2 = *(const float4*)(xb + 2 * HW + p4);
            float a0[4] = {v0.x, v0.y, v0.z, v0.w};
            float a1[4] = {v1.x, v1.y, v1.z, v1.w};
            float a2[4] = {v2.x, v2.y, v2.z, v2.w};
            #pragma unroll
            for (int t = 0; t < 4; t++) {
                #pragma unroll
                for (int c = 0; c < 4; c++) {
                    float a = fmaf(wr[c][0], a0[t], fmaf(wr[c][1], a1[t], wr[c][2] * a2[t]));
                    s1 += a; s2 += a * a;
                }
            }
        }
    }
    bred2(s1, s2, red);  // barrier also orders zero-init before interior writes
    const float mean = s1 / (4.f * HW);
    const float var = s2 / (4.f * HW) - mean * mean;
    const float inv = rsqrtf(var + 1e-5f);

    float dacc[4][7];
    float t1 = 0.f, t2 = 0.f;
    for (int c = 0; c < 4; c++) {  // uniform: scale/weight loads are scalar
        const float sc1 = g1s[e * CEXP + g * 4 + c];
        const float bi1 = g1b[e * CEXP + g * 4 + c];
        __syncthreads();  // previous channel's dw reads complete
        #pragma unroll
        for (int j = 0; j < 7; j++) {
            if (j < 6 || tid < 64) {
                int p4 = (j * TPB + tid) * 4;
                int ph = p4 / W, pwb = p4 - ph * W;
                float4 v0 = *(const float4*)(xb + p4);
                float4 v1 = *(const float4*)(xb + HW + p4);
                float4 v2 = *(const float4*)(xb + 2 * HW + p4);
                float a0[4] = {v0.x, v0.y, v0.z, v0.w};
                float a1[4] = {v1.x, v1.y, v1.z, v1.w};
                float a2[4] = {v2.x, v2.y, v2.z, v2.w};
                #pragma unroll
                for (int t = 0; t < 4; t++) {
                    float a = fmaf(wr[c][0], a0[t], fmaf(wr[c][1], a1[t], wr[c][2] * a2[t]));
                    float v = silu_f((a - mean) * inv * sc1 + bi1);
                    int j2 = pwb + t + 3;
                    buf1[(ph + 3) * RW + ((j2 & 1) ? EV + (j2 >> 1) : (j2 >> 1))] = v;
                }
            }
        }
        __syncthreads();
        const float* w2c = w2 + ((size_t)e * CEXP + g * 4 + c) * 49;
        #pragma unroll
        for (int j = 0; j < 7; j++) {
            dacc[c][j] = 0.f;
            if (j < 6 || tid < 64) {
                int o = j * TPB + tid;
                int oh = o / WO, ow = o - oh * WO;
                float a = 0.f;
                #pragma unroll
                for (int kh = 0; kh < KS; kh++) {
                    const int base = (2 * oh + kh) * RW + ow;
                    a = fmaf(w2c[kh * 7 + 0], buf1[base + 0], a);
                    a = fmaf(w2c[kh * 7 + 1], buf1[base + EV + 0], a);
                    a = fmaf(w2c[kh * 7 + 2], buf1[base + 1], a);
                    a = fmaf(w2c[kh * 7 + 3], buf1[base + EV + 1], a);
                    a = fmaf(w2c[kh * 7 + 4], buf1[base + 2], a);
                    a = fmaf(w2c[kh * 7 + 5], buf1[base + EV + 2], a);
                    a = fmaf(w2c[kh * 7 + 6], buf1[base + 3], a);
                }
                dacc[c][j] = a; t1 += a; t2 += a * a;
            }
        }
    }
    bred2(t1, t2, red);
    const float mean2 = t1 / (4.f * HWO);
    const float var2 = t2 / (4.f * HWO) - mean2 * mean2;
    const float inv2 = rsqrtf(var2 + 1e-5f);
    float* ao = act2 + ((size_t)(b * 2 + slot) * CEXP + g * 4) * HWO;
    for (int c = 0; c < 4; c++) {
        const float sc2 = g2s[e * CEXP + g * 4 + c];
        const float bi2 = g2b[e * CEXP + g * 4 + c];
        #pragma unroll
        for (int j = 0; j < 7; j++) {
            if (j < 6 || tid < 64) {
                int o = j * TPB + tid;
                ao[c * HWO + o] = silu_f((dacc[c][j] - mean2) * inv2 * sc2 + bi2);
            }
        }
    }
}

// pw3 -> GN -> gate-weighted sum over 2 slots, one (batch, 4-out-ch group).
template <int CEXP, int COUT, int HWO>
__global__ __launch_bounds__(TPB) void dsc_c(
    const float* __restrict__ act2, const float* __restrict__ w3,
    const float* __restrict__ g3s, const float* __restrict__ g3b,
    const int* __restrict__ gidx, const float* __restrict__ gw,
    float* __restrict__ xout) {
    constexpr int PXT = (HWO + TPB - 1) / TPB;
    const int b = blockIdx.x, go = blockIdx.y;
    const int tid = threadIdx.x;
    __shared__ float red[2 * (TPB / 64)];

    float out[4][PXT];
    #pragma unroll
    for (int c = 0; c < 4; c++)
        #pragma unroll
        for (int j = 0; j < PXT; j++) out[c][j] = 0.f;

    for (int slot = 0; slot < 2; slot++) {
        const int e = rfl(gidx[b * 2 + slot]);
        const float wgt = rflf(gw[b * 2 + slot]);
        const float* w3e = w3 + ((size_t)e * COUT + go * 4) * CEXP;
        const float* ab = act2 + (size_t)(b * 2 + slot) * CEXP * HWO;

        float acc[4][PXT];
        #pragma unroll
        for (int c = 0; c < 4; c++)
            #pragma unroll
            for (int j = 0; j < PXT; j++) acc[c][j] = 0.f;

        for (int cb = 0; cb < CEXP; cb += 16) {
            float wr[4][16];
            #pragma unroll
            for (int c = 0; c < 4; c++)
                #pragma unroll
                for (int k = 0; k < 16; k++) wr[c][k] = w3e[c * CEXP + cb + k];
            #pragma unroll
            for (int j = 0; j < PXT; j++) {
                int p = tid + j * TPB;
                if (PXT * TPB == HWO || p < HWO) {
                    #pragma unroll
                    for (int k = 0; k < 16; k++) {
                        float v = ab[(size_t)(cb + k) * HWO + p];
                        #pragma unroll
                        for (int c = 0; c < 4; c++) acc[c][j] = fmaf(wr[c][k], v, acc[c][j]);
                    }
                }
            }
        }
        float s1 = 0.f, s2 = 0.f;
        #pragma unroll
        for (int c = 0; c < 4; c++)
            #pragma unroll
            for (int j = 0; j < PXT; j++) { s1 += acc[c][j]; s2 += acc[c][j] * acc[c][j]; }
        bred2(s1, s2, red);
        const float mean = s1 / (4.f * HWO);
        const float var = s2 / (4.f * HWO) - mean * mean;
        const float inv = rsqrtf(var + 1e-5f);
        float scr[4], bir[4];
        #pragma unroll
        for (int c = 0; c < 4; c++) {
            scr[c] = g3s[e * COUT + go * 4 + c];
            bir[c] = g3b[e * COUT + go * 4 + c];
        }
        #pragma unroll
        for (int c = 0; c < 4; c++)
            #pragma unroll
            for (int j = 0; j < PXT; j++)
                out[c][j] += wgt * ((acc[c][j] - mean) * inv * scr[c] + bir[c]);
    }
    float* xo = xout + ((size_t)b * COUT + go * 4) * HWO;
    #pragma unroll
    for (int c = 0; c < 4; c++)
        #pragma unroll
        for (int j = 0; j < PXT; j++) {
            int p = tid + j * TPB;
            if (PXT * TPB == HWO || p < HWO) xo[c * HWO + p] = out[c][j];
        }
}

// patchify (B,32,20,20) -> (B,25,512) + pos embed; writes scalar loss=0.
__global__ void patchify_kernel(const float* __restrict__ x, const float* __restrict__ ppe,
                                float* __restrict__ out) {
    const int idx = blockIdx.x * TPB + threadIdx.x;
    if (idx < 64 * 25 * 512) {
        int d = idx & 511;
        int p = (idx >> 9) % 25;
        int b = idx / (25 * 512);
        int c = d & 31;
        int j = (d >> 5) & 3;
        int i = d >> 7;
        int ph = p / 5, pw = p % 5;
        out[idx] = x[((b * 32 + c) * 20 + ph * 4 + i) * 20 + pw * 4 + j] + ppe[p * 512 + d];
    }
    if (idx == 0) out[64 * 25 * 512] = 0.f;
}

extern "C" void kernel_launch(void* const* d_in, const int* in_sizes, int n_in,
                              void* d_out, int out_size, void* d_ws, size_t ws_size,
                              hipStream_t stream) {
    const float* gate_input = (const float*)d_in[0];
    const float* expert_input = (const float*)d_in[1];
    const float* ppe = (const float*)d_in[2];
    const int* taskp = (const int*)d_in[53];
    auto in = [&](int s, int k) { return (const float*)d_in[3 + s * 10 + k]; };
    // k: 0 wg, 1 w1, 2 g1s, 3 g1b, 4 w2, 5 g2s, 6 g2b, 7 w3, 8 g3s, 9 g3b

    char* ws = (char*)d_ws;
    int* gidx = (int*)ws;
    float* gw = (float*)(ws + 4096);
    float* x0 = (float*)(ws + 8192);
    float* x1 = (float*)(ws + 8192 + 13631488);
    float* act2 = (float*)(ws + 8192 + 2 * 13631488);

    GatePtrs gp;
    for (int s = 0; s < 5; s++) gp.wg[s] = in(s, 0);
    gate_kernel<<<5, 64, 0, stream>>>(gate_input, gp, taskp, gidx, gw);

    // Stage 1: (B,3,80,80) -> (B,16,40,40)  [k=7, s=2]
    dsc_ab_s1<<<dim3(64, 2, 8), TPB, 0, stream>>>(
        expert_input, in(0, 1), in(0, 2), in(0, 3), in(0, 4), in(0, 5), in(0, 6),
        gidx + 0 * 128, act2);
    dsc_c<32, 16, 1600><<<dim3(64, 4), TPB, 0, stream>>>(
        act2, in(0, 7), in(0, 8), in(0, 9), gidx + 0 * 128, gw + 0 * 128, x0);

    // Stage 2: (B,16,40,40) -> (B,32,40,40)  [k=3, s=1]
    dsc_ab4<16, 64, 3, 1, 40, 40, 40, 40><<<dim3(64, 2, 16), TPB, 0, stream>>>(
        x0, in(1, 1), in(1, 2), in(1, 3), in(1, 4), in(1, 5), in(1, 6),
        gidx + 1 * 128, act2);
    dsc_c<64, 32, 1600><<<dim3(64, 8), TPB, 0, stream>>>(
        act2, in(1, 7), in(1, 8), in(1, 9), gidx + 1 * 128, gw + 1 * 128, x1);

    // Stage 3: (B,32,40,40) -> (B,64,20,20)  [k=3, s=2]
    dsc_ab4<32, 128, 3, 2, 40, 40, 20, 20><<<dim3(64, 2, 32), TPB, 0, stream>>>(
        x1, in(2, 1), in(2, 2), in(2, 3), in(2, 4), in(2, 5), in(2, 6),
        gidx + 2 * 128, act2);
    dsc_c<128, 64, 400><<<dim3(64, 16), TPB, 0, stream>>>(
        act2, in(2, 7), in(2, 8), in(2, 9), gidx + 2 * 128, gw + 2 * 128, x0);

    // Stage 4: (B,64,20,20) -> (B,64,20,20)  [k=3, s=1]
    dsc_ab4<64, 256, 3, 1, 20, 20, 20, 20><<<dim3(64, 2, 64), TPB, 0, stream>>>(
        x0, in(3, 1), in(3, 2), in(3, 3), in(3, 4), in(3, 5), in(3, 6),
        gidx + 3 * 128, act2);
    dsc_c<256, 64, 400><<<dim3(64, 16), TPB, 0, stream>>>(
        act2, in(3, 7), in(3, 8), in(3, 9), gidx + 3 * 128, gw + 3 * 128, x1);

    // Stage 5: (B,64,20,20) -> (B,32,20,20)  [k=3, s=1]
    dsc_ab4<64, 128, 3, 1, 20, 20, 20, 20><<<dim3(64, 2, 32), TPB, 0, stream>>>(
        x1, in(4, 1), in(4, 2), in(4, 3), in(4, 4), in(4, 5), in(4, 6),
        gidx + 4 * 128, act2);
    dsc_c<128, 32, 400><<<dim3(64, 8), TPB, 0, stream>>>(
        act2, in(4, 7), in(4, 8), in(4, 9), gidx + 4 * 128, gw + 4 * 128, x0);

    patchify_kernel<<<(64 * 25 * 512 + TPB - 1) / TPB, TPB, 0, stream>>>(x0, ppe, (float*)d_out);
}